// Round 9
// baseline (407.869 us; speedup 1.0000x reference)
//
#include <hip/hip_runtime.h>
#include <hip/hip_fp16.h>
#include <math.h>

#define Bsz 2
#define Nn 2048
#define Dd 256
#define Hh 4
#define DHh 64
#define Jj 32
#define CE 274      // 2*EIN = 274
#define CEP 288     // padded to multiple of 32 (9 MFMA K-steps)
#define NCOMB 2448  // 4*274 (q) + 4*274 (k) + 256 (v)
#define NPAD 2560   // padded to 20*128

typedef _Float16 f16x8 __attribute__((ext_vector_type(8)));
typedef _Float16 f16x4 __attribute__((ext_vector_type(4)));
typedef __attribute__((ext_vector_type(4))) float f32x4;

__device__ __forceinline__ float4 ld4(const float* p) { return *reinterpret_cast<const float4*>(p); }

// ---------------------------------------------------------------------------
// K0 k_fold: WcombT[col][k] fp16, col layout: [q: h*274+m | k: +1096 | v: +2192]
// grid 2560 blocks x 256 threads (thread = kk)
// ---------------------------------------------------------------------------
__global__ __launch_bounds__(256) void k_fold(const float* __restrict__ w_qkv,
                                              const float* __restrict__ w_e1,
                                              _Float16* __restrict__ WcombT) {
    const int col = blockIdx.x;
    const int kk = threadIdx.x;
    float val = 0.f;
    if (col < 2192) {
        const int p = (col >= 1096) ? 1 : 0;
        const int c2 = col - p * 1096;
        const int h = c2 / 274;
        const int m = c2 - h * 274;
        const float* wq = w_qkv + (size_t)kk * 768 + p * 256 + h * 64;
        const float* we = w_e1 + (size_t)(p * 64) * CE + m;
#pragma unroll 8
        for (int d = 0; d < 64; ++d) val += wq[d] * we[(size_t)d * CE];
    } else if (col < NCOMB) {
        val = w_qkv[(size_t)kk * 768 + 512 + (col - 2192)];
    }
    WcombT[(size_t)col * 256 + kk] = (_Float16)val;
}

// ---------------------------------------------------------------------------
// K1 k_main: C[4096][2560] = feats_f16 @ Wcomb ; epilogue scatters to
// qproj/kproj (fp16, [bh][2048][288], +b_e1 on q) and vbuf (fp16 [bh][2048][64]).
// fp16 MFMA 16x16x32. block 256 = 4 waves (2x2), tile 128x128, K-step 32.
// grid (20, 32).
// ---------------------------------------------------------------------------
__global__ __launch_bounds__(256) void k_main(const float* __restrict__ feats,
                                              const _Float16* __restrict__ WcombT,
                                              const float* __restrict__ b_e1,
                                              _Float16* __restrict__ qproj,
                                              _Float16* __restrict__ kproj,
                                              _Float16* __restrict__ vbuf) {
    __shared__ _Float16 As[128][40];
    __shared__ _Float16 Bs[128][40];
    const int t = threadIdx.x;
    const int bn = blockIdx.x * 128;
    const int bm = blockIdx.y * 128;
    const int wid = t >> 6, lane = t & 63, lg = lane >> 4, lr = lane & 15;
    const int wm = wid >> 1, wn = wid & 1;

    f32x4 acc[4][4] = {};
    for (int k0 = 0; k0 < 256; k0 += 32) {
        // stage A: 128 rows x 32 k (f32 -> f16)
#pragma unroll
        for (int it = 0; it < 4; ++it) {
            const int idx = it * 256 + t;
            const int row = idx >> 3, kq = (idx & 7) << 2;
            const float4 a = ld4(&feats[(size_t)(bm + row) * 256 + k0 + kq]);
            f16x4 w;
            w[0] = (_Float16)a.x; w[1] = (_Float16)a.y;
            w[2] = (_Float16)a.z; w[3] = (_Float16)a.w;
            *reinterpret_cast<f16x4*>(&As[row][kq]) = w;
        }
        // stage B: 128 cols x 32 k (fp16 direct, WcombT rows)
#pragma unroll
        for (int it = 0; it < 2; ++it) {
            const int idx = it * 256 + t;
            const int nl = idx >> 2, kq = (idx & 3) << 3;
            *reinterpret_cast<uint4*>(&Bs[nl][kq]) =
                *reinterpret_cast<const uint4*>(&WcombT[(size_t)(bn + nl) * 256 + k0 + kq]);
        }
        __syncthreads();
        f16x8 af[4], bf[4];
#pragma unroll
        for (int mi = 0; mi < 4; ++mi)
            af[mi] = *reinterpret_cast<const f16x8*>(&As[wm * 64 + mi * 16 + lr][lg * 8]);
#pragma unroll
        for (int ni = 0; ni < 4; ++ni)
            bf[ni] = *reinterpret_cast<const f16x8*>(&Bs[wn * 64 + ni * 16 + lr][lg * 8]);
#pragma unroll
        for (int mi = 0; mi < 4; ++mi)
#pragma unroll
            for (int ni = 0; ni < 4; ++ni)
                acc[mi][ni] = __builtin_amdgcn_mfma_f32_16x16x32_f16(af[mi], bf[ni], acc[mi][ni], 0, 0, 0);
        __syncthreads();
    }
    // epilogue
#pragma unroll
    for (int ni = 0; ni < 4; ++ni) {
        const int col = bn + wn * 64 + ni * 16 + lr;
        int sect, h, m;
        float bias = 0.f;
        if (col < 1096) {
            sect = 0; h = col / 274; m = col - h * 274; bias = b_e1[m];
        } else if (col < 2192) {
            const int c2 = col - 1096; sect = 1; h = c2 / 274; m = c2 - h * 274;
        } else if (col < NCOMB) {
            const int c2 = col - 2192; sect = 2; h = c2 >> 6; m = c2 & 63;
        } else {
            sect = 3; h = 0; m = 0;
        }
#pragma unroll
        for (int mi = 0; mi < 4; ++mi) {
            const f32x4 C = acc[mi][ni];
#pragma unroll
            for (int r = 0; r < 4; ++r) {
                const int row = bm + wm * 64 + mi * 16 + lg * 4 + r;
                const int bb = row >> 11, n = row & 2047;
                const float val = C[r] + bias;
                if (sect == 0)
                    qproj[((size_t)(bb * 4 + h) * 2048 + n) * CEP + m] = (_Float16)val;
                else if (sect == 1)
                    kproj[((size_t)(bb * 4 + h) * 2048 + n) * CEP + m] = (_Float16)val;
                else if (sect == 2)
                    vbuf[((size_t)(bb * 4 + h) * 2048 + n) * 64 + m] = (_Float16)val;
            }
        }
    }
}

// ---------------------------------------------------------------------------
// K2 k_edge4: fp16 MFMA edge kernel. Wave = one (b,i), 4 heads, 32 j.
// Block = 4 waves. grid 1024. qp hoisted across tt; packed-f16 A-build;
// K=16 MFMA (legacy builtin mfma_f32_16x16x16f16) for a/c heads.
// NOTE: qproj/kproj pad cols 274..287 are unwritten poison; safe because
// s_we2f zeroes those columns in the B-frag, so their product contribution
// is exactly 0 regardless of A content.
// ---------------------------------------------------------------------------
__global__ __launch_bounds__(256, 5) void k_edge4(
    const float* __restrict__ coors, const int* __restrict__ nbhd,
    const _Float16* __restrict__ qproj, const _Float16* __restrict__ kproj,
    const _Float16* __restrict__ vbuf, const float* __restrict__ basis,
    const float* __restrict__ w_e1, const float* __restrict__ w_e2, const float* __restrict__ b_e2,
    const float* __restrict__ w_a1, const float* __restrict__ b_a1, const float* __restrict__ w_a2,
    const float* __restrict__ w_c1, const float* __restrict__ b_c1, const float* __restrict__ w_c2,
    const float* __restrict__ b_c2,
    float* __restrict__ out_tmp, float* __restrict__ coors_out) {

    __shared__ float s_we1r[9][CEP];                 // 10368 B (cols >= CE zeroed)
    __shared__ _Float16 s_we2f[9 * 64 * 8];          // 9216 B
    __shared__ _Float16 s_wacf[2 * 4 * 64 * 4];      // 4096 B (K=16, no padding)
    __shared__ _Float16 s_m16[4][16][20];            // 2560 B
    __shared__ float s_ba1[64], s_wa2[64], s_bc1[64], s_wc2[64]; // 1024 B
    __shared__ float s_attn[4][2][16];               // 512 B
    __shared__ int   s_nb[4][2][16];                 // 512 B  -> 28288 B

    const int t = threadIdx.x;
    const int blk0 = blockIdx.x;
    const int blk = (blk0 & 7) * 128 + (blk0 >> 3);   // XCD swizzle (1024 % 8 == 0)
    const int b = blk >> 9;
    const int ichunk = blk & 511;
    const int wid = t >> 6, lane = t & 63;
    const int lg = lane >> 4, lr = lane & 15;
    const int i = ichunk * 4 + wid;

    // ---- stage weights ----
    for (int x = t; x < 9 * CEP; x += 256) {
        const int r = x / CEP, c = x - r * CEP;
        s_we1r[r][c] = (c < CE) ? w_e1[(128 + r) * CE + c] : 0.f;
    }
    for (int x = t; x < 9 * 64 * 8; x += 256) {
        const int kk = x >> 9, rem = x & 511, ln = rem >> 3, e = rem & 7;
        const int c = kk * 32 + (ln >> 4) * 8 + e;
        s_we2f[x] = (_Float16)((c < CE) ? w_e2[c * 16 + (ln & 15)] : 0.f);
    }
    for (int x = t; x < 2 * 4 * 64 * 4; x += 256) {
        const int w01 = x >> 10, rem = x & 1023;
        const int ut = rem >> 8, ln = (rem >> 2) & 63, e = x & 3;
        const int kidx = (ln >> 4) * 4 + e;   // 0..15, all valid
        s_wacf[x] = (_Float16)((w01 ? w_c1 : w_a1)[kidx * 64 + ut * 16 + (ln & 15)]);
    }
    if (t < 64) { s_ba1[t] = b_a1[t]; s_wa2[t] = w_a2[t]; s_bc1[t] = b_c1[t]; s_wc2[t] = w_c2[t]; }
    __syncthreads();

    const float be2v = b_e2[lr];
    const float bc2v = b_c2[0];

    const float cx = coors[((size_t)b * Nn + i) * 3 + 0];
    const float cy = coors[((size_t)b * Nn + i) * 3 + 1];
    const float cz = coors[((size_t)b * Nn + i) * 3 + 2];

    // ---- per-edge setup for both tt tiles ----
    float renc[2][9];
    float bas[2][3];
    const _Float16* kpb[2];
#pragma unroll
    for (int tt = 0; tt < 2; ++tt) {
        const int j = tt * 16 + lr;
        const int nb = nbhd[((size_t)b * Nn + i) * Jj + j];
        if (lg == 0) s_nb[wid][tt][lr] = nb;
        const float dx = cx - coors[((size_t)b * Nn + nb) * 3 + 0];
        const float dy = cy - coors[((size_t)b * Nn + nb) * 3 + 1];
        const float dz = cz - coors[((size_t)b * Nn + nb) * 3 + 2];
        const float d2 = dx * dx + dy * dy + dz * dz;
        bas[tt][0] = basis[((size_t)((size_t)b * Nn + i) * Nn + nb) * 3 + 0];
        bas[tt][1] = basis[((size_t)((size_t)b * Nn + i) * Nn + nb) * 3 + 1];
        bas[tt][2] = basis[((size_t)((size_t)b * Nn + i) * Nn + nb) * 3 + 2];
        float s = 1.f;
#pragma unroll
        for (int f = 0; f < 4; ++f) {
            float sv, cv;
            sincosf(d2 * s, &sv, &cv);
            renc[tt][f] = sv;
            renc[tt][4 + f] = cv;
            s *= 0.5f;
        }
        renc[tt][8] = d2;
        kpb[tt] = kproj + ((size_t)(b * Hh) * Nn + nb) * CEP;
    }
    const _Float16* qpb = qproj + ((size_t)(b * Hh) * Nn + i) * CEP;
    const size_t hstride = (size_t)Nn * CEP;

    f32x4 C[2][4] = {};
    const f16x8 zf8 = {0, 0, 0, 0, 0, 0, 0, 0};

    // ---- main loop: kk outer, qp hoisted across tt ----
    for (int kk = 0; kk < 9; ++kk) {
        const int c0 = kk * 32 + lg * 8;
        f16x8 qpv[4];
#pragma unroll
        for (int h = 0; h < 4; ++h)
            qpv[h] = *reinterpret_cast<const f16x8*>(qpb + (size_t)h * hstride + c0);
        const f16x8 bfrag = *reinterpret_cast<const f16x8*>(&s_we2f[(kk * 64 + lane) * 8]);
#pragma unroll
        for (int tt = 0; tt < 2; ++tt) {
            f32x4 rpa = {0.f, 0.f, 0.f, 0.f};
            f32x4 rpb = {0.f, 0.f, 0.f, 0.f};
#pragma unroll
            for (int r = 0; r < 9; ++r) {
                const f32x4 wa = *reinterpret_cast<const f32x4*>(&s_we1r[r][c0]);
                const f32x4 wb = *reinterpret_cast<const f32x4*>(&s_we1r[r][c0 + 4]);
                const float e = renc[tt][r];
                rpa += e * wa;
                rpb += e * wb;
            }
            f16x8 rp;
#pragma unroll
            for (int e = 0; e < 4; ++e) { rp[e] = (_Float16)rpa[e]; rp[4 + e] = (_Float16)rpb[e]; }
#pragma unroll
            for (int h = 0; h < 4; ++h) {
                const f16x8 kpv = *reinterpret_cast<const f16x8*>(kpb[tt] + (size_t)h * hstride + c0);
                f16x8 A = qpv[h] + kpv + rp;
                A = __builtin_elementwise_max(A, zf8);
                C[tt][h] = __builtin_amdgcn_mfma_f32_16x16x32_f16(A, bfrag, C[tt][h], 0, 0, 0);
            }
        }
    }

    // ---- m roundtrip + a/c heads (per tt, h) ----
    float sim[2][4], cw[2][4];
#pragma unroll
    for (int tt = 0; tt < 2; ++tt) {
#pragma unroll
        for (int h = 0; h < 4; ++h) {
            const f32x4 Ch = C[tt][h];
#pragma unroll
            for (int r = 0; r < 4; ++r)
                s_m16[wid][lg * 4 + r][lr] = (_Float16)fmaxf(Ch[r] + be2v, 0.f);
            const f16x4 Bm = *reinterpret_cast<const f16x4*>(&s_m16[wid][lr][lg * 4]);
            float sa = 0.f, sc = 0.f;
#pragma unroll
            for (int ut = 0; ut < 4; ++ut) {
                const f16x4 fa = *reinterpret_cast<const f16x4*>(&s_wacf[((0 * 4 + ut) * 64 + lane) * 4]);
                const f16x4 fc = *reinterpret_cast<const f16x4*>(&s_wacf[((1 * 4 + ut) * 64 + lane) * 4]);
                f32x4 ca = *reinterpret_cast<const f32x4*>(&s_ba1[ut * 16 + lg * 4]);
                f32x4 cc = *reinterpret_cast<const f32x4*>(&s_bc1[ut * 16 + lg * 4]);
                ca = __builtin_amdgcn_mfma_f32_16x16x16f16(fa, Bm, ca, 0, 0, 0);
                cc = __builtin_amdgcn_mfma_f32_16x16x16f16(fc, Bm, cc, 0, 0, 0);
                const f32x4 w2a = *reinterpret_cast<const f32x4*>(&s_wa2[ut * 16 + lg * 4]);
                const f32x4 w2c = *reinterpret_cast<const f32x4*>(&s_wc2[ut * 16 + lg * 4]);
#pragma unroll
                for (int r = 0; r < 4; ++r) {
                    sa += fmaxf(ca[r], 0.f) * w2a[r];
                    sc += fmaxf(cc[r], 0.f) * w2c[r];
                }
            }
            sa += __shfl_xor(sa, 16); sa += __shfl_xor(sa, 32);
            sc += __shfl_xor(sc, 16); sc += __shfl_xor(sc, 32);
            sim[tt][h] = sa;
            cw[tt][h] = sc + bc2v;
        }
    }

    // ---- softmax + PV + coors (per head) ----
    float px = 0.f, py = 0.f, pz = 0.f;
#pragma unroll
    for (int h = 0; h < 4; ++h) {
        float mx = fmaxf(sim[0][h], sim[1][h]);
        mx = fmaxf(mx, __shfl_xor(mx, 8));
        mx = fmaxf(mx, __shfl_xor(mx, 4));
        mx = fmaxf(mx, __shfl_xor(mx, 2));
        mx = fmaxf(mx, __shfl_xor(mx, 1));
        const float e0 = __expf(sim[0][h] - mx);
        const float e1 = __expf(sim[1][h] - mx);
        float S = e0 + e1;
        S += __shfl_xor(S, 8); S += __shfl_xor(S, 4);
        S += __shfl_xor(S, 2); S += __shfl_xor(S, 1);
        const float inv = 1.f / S;
        if (lg == 0) { s_attn[wid][0][lr] = e0 * inv; s_attn[wid][1][lr] = e1 * inv; }

        px += cw[0][h] * bas[0][0] + cw[1][h] * bas[1][0];
        py += cw[0][h] * bas[0][1] + cw[1][h] * bas[1][1];
        pz += cw[0][h] * bas[0][2] + cw[1][h] * bas[1][2];

        const _Float16* vb = vbuf + (size_t)(b * Hh + h) * Nn * DHh;
        float4 acc = {0.f, 0.f, 0.f, 0.f};
#pragma unroll
        for (int jj = 0; jj < 8; ++jj) {
            const int j2 = lg * 8 + jj;
            const float a = s_attn[wid][j2 >> 4][j2 & 15];
            const int nb2 = s_nb[wid][j2 >> 4][j2 & 15];
            const f16x4 vv = *reinterpret_cast<const f16x4*>(vb + (size_t)nb2 * DHh + lr * 4);
            acc.x += a * (float)vv[0]; acc.y += a * (float)vv[1];
            acc.z += a * (float)vv[2]; acc.w += a * (float)vv[3];
        }
        acc.x += __shfl_xor(acc.x, 16); acc.x += __shfl_xor(acc.x, 32);
        acc.y += __shfl_xor(acc.y, 16); acc.y += __shfl_xor(acc.y, 32);
        acc.z += __shfl_xor(acc.z, 16); acc.z += __shfl_xor(acc.z, 32);
        acc.w += __shfl_xor(acc.w, 16); acc.w += __shfl_xor(acc.w, 32);
        if (lane < 16)
            *reinterpret_cast<float4*>(&out_tmp[(((size_t)b * Nn + i) * Hh + h) * DHh + lr * 4]) = acc;
    }
    px += __shfl_xor(px, 1); px += __shfl_xor(px, 2); px += __shfl_xor(px, 4); px += __shfl_xor(px, 8);
    py += __shfl_xor(py, 1); py += __shfl_xor(py, 2); py += __shfl_xor(py, 4); py += __shfl_xor(py, 8);
    pz += __shfl_xor(pz, 1); pz += __shfl_xor(pz, 2); pz += __shfl_xor(pz, 4); pz += __shfl_xor(pz, 8);
    if (lane == 0) {
        coors_out[((size_t)b * Nn + i) * 3 + 0] = px;
        coors_out[((size_t)b * Nn + i) * 3 + 1] = py;
        coors_out[((size_t)b * Nn + i) * 3 + 2] = pz;
    }
}

// ---------------------------------------------------------------------------
// K3 k_out: out = tmp(4096x256) @ w_out(256x256) + b_out  (fp32, unchanged)
// grid (4, 64), block 256
// ---------------------------------------------------------------------------
__global__ __launch_bounds__(256) void k_out(const float* __restrict__ tmp,
                                             const float* __restrict__ w,
                                             const float* __restrict__ bias,
                                             float* __restrict__ outp) {
    __shared__ float As[32][68];
    __shared__ float Bs[32][68];
    const int t = threadIdx.x;
    const int bn = blockIdx.x * 64;
    const int bm = blockIdx.y * 64;
    const int tn = t & 15, tm = t >> 4;
    const int ml = t >> 3, kl = (t & 7) << 2;
    const int kl2 = t >> 4, nl = (t & 15) << 2;
    float acc[4][4] = {};
    for (int k0 = 0; k0 < 256; k0 += 32) {
        float4 a0 = ld4(&tmp[(size_t)(bm + ml) * 256 + k0 + kl]);
        float4 a1 = ld4(&tmp[(size_t)(bm + ml + 32) * 256 + k0 + kl]);
        As[kl + 0][ml] = a0.x; As[kl + 1][ml] = a0.y; As[kl + 2][ml] = a0.z; As[kl + 3][ml] = a0.w;
        As[kl + 0][ml + 32] = a1.x; As[kl + 1][ml + 32] = a1.y; As[kl + 2][ml + 32] = a1.z; As[kl + 3][ml + 32] = a1.w;
        *reinterpret_cast<float4*>(&Bs[kl2][nl])      = ld4(&w[(size_t)(k0 + kl2) * 256 + bn + nl]);
        *reinterpret_cast<float4*>(&Bs[kl2 + 16][nl]) = ld4(&w[(size_t)(k0 + kl2 + 16) * 256 + bn + nl]);
        __syncthreads();
#pragma unroll
        for (int kk = 0; kk < 32; ++kk) {
            const float4 a = ld4(&As[kk][tm * 4]);
            const float4 bb = ld4(&Bs[kk][tn * 4]);
            const float av[4] = {a.x, a.y, a.z, a.w};
            const float bv[4] = {bb.x, bb.y, bb.z, bb.w};
#pragma unroll
            for (int mi = 0; mi < 4; ++mi)
#pragma unroll
                for (int ni = 0; ni < 4; ++ni) acc[mi][ni] += av[mi] * bv[ni];
        }
        __syncthreads();
    }
    const int c = bn + tn * 4;
    const float4 bv4 = ld4(&bias[c]);
#pragma unroll
    for (int mi = 0; mi < 4; ++mi) {
        const int row = bm + tm * 4 + mi;
        float4 o = {acc[mi][0] + bv4.x, acc[mi][1] + bv4.y, acc[mi][2] + bv4.z, acc[mi][3] + bv4.w};
        *reinterpret_cast<float4*>(&outp[(size_t)row * 256 + c]) = o;
    }
}

// ---------------------------------------------------------------------------
extern "C" void kernel_launch(void* const* d_in, const int* in_sizes, int n_in,
                              void* d_out, int out_size, void* d_ws, size_t ws_size,
                              hipStream_t stream) {
    const float* feats = (const float*)d_in[0];
    const float* coors = (const float*)d_in[1];
    const float* basis = (const float*)d_in[2];
    const int* nbhd = (const int*)d_in[3];
    const float* w_qkv = (const float*)d_in[4];
    const float* w_out = (const float*)d_in[5];
    const float* b_out = (const float*)d_in[6];
    const float* w_e1 = (const float*)d_in[7];
    const float* b_e1 = (const float*)d_in[8];
    const float* w_e2 = (const float*)d_in[9];
    const float* b_e2 = (const float*)d_in[10];
    const float* w_a1 = (const float*)d_in[11];
    const float* b_a1 = (const float*)d_in[12];
    const float* w_a2 = (const float*)d_in[13];
    /* b_a2 (d_in[14]) unused: constant bias cancels in softmax */
    const float* w_c1 = (const float*)d_in[15];
    const float* b_c1 = (const float*)d_in[16];
    const float* w_c2 = (const float*)d_in[17];
    const float* b_c2 = (const float*)d_in[18];

    _Float16* WcombT = (_Float16*)d_ws;                         // 2560*256 halves
    _Float16* qproj = WcombT + (size_t)NPAD * 256;              // 8*2048*288
    _Float16* kproj = qproj + (size_t)Bsz * Hh * Nn * CEP;      // 8*2048*288
    _Float16* vbuf  = kproj + (size_t)Bsz * Hh * Nn * CEP;      // 8*2048*64
    float* tmp = (float*)(vbuf + (size_t)Bsz * Hh * Nn * DHh);  // 4096*256 f32

    float* outp = (float*)d_out;
    float* coors_out = outp + (size_t)Bsz * Nn * Dd;

    hipLaunchKernelGGL(k_fold, dim3(NPAD), dim3(256), 0, stream, w_qkv, w_e1, WcombT);
    hipLaunchKernelGGL(k_main, dim3(20, 32), dim3(256), 0, stream,
                       feats, WcombT, b_e1, qproj, kproj, vbuf);
    hipLaunchKernelGGL(k_edge4, dim3(1024), dim3(256), 0, stream,
                       coors, nbhd, qproj, kproj, vbuf, basis,
                       w_e1, w_e2, b_e2, w_a1, b_a1, w_a2,
                       w_c1, b_c1, w_c2, b_c2, tmp, coors_out);
    hipLaunchKernelGGL(k_out, dim3(4, 64), dim3(256), 0, stream, tmp, w_out, b_out, outp);
}